// Round 1
// 133.076 us; speedup vs baseline: 1.0773x; 1.0773x over previous
//
#include <hip/hip_runtime.h>

#define B_      128
#define C_IN_   256
#define NPTS    1024
#define C_OUT_  256
#define L_      3069
#define NTRIP   1023
#define T_OUT   1024
#define FEATS_SIZE (B_ * C_OUT_ * T_OUT)
#define KTOT    768

#define BK      96          // 32 channels * 3 taps
#define NCHUNK  8           // 768 / 96
#define THREADS 512

typedef __attribute__((ext_vector_type(8))) short           bf16x8;
typedef __attribute__((ext_vector_type(8))) unsigned short  ushort8;
typedef __attribute__((ext_vector_type(4))) unsigned short  ushort4v;
typedef __attribute__((ext_vector_type(4))) float           f32x4;

__device__ __forceinline__ unsigned short f2bf(float f) {
    union { float f; unsigned u; } v; v.f = f;
    unsigned r = (v.u + 0x7FFFu + ((v.u >> 16) & 1u)) >> 16;   // RNE
    return (unsigned short)r;
}

__device__ __forceinline__ void gload16(const void* g, void* l) {
    __builtin_amdgcn_global_load_lds(
        (const __attribute__((address_space(1))) unsigned int*)g,
        (__attribute__((address_space(3))) unsigned int*)l, 16, 0, 0);
}

// ===================== TIER 2 (fast path) =====================
// ws layout: [0, 393216): wbf2  — weights bf16, tap-major K, per-chunk,
//                          pre-swizzled so a LINEAR copy into LDS yields the
//                          swizzled image the fragment reads expect.
//            [393216, +67108864): dataT — bf16 [b][n][c]
#define WOFF_T  0
#define DOFF_T  393216
#define WS_NEED_T2 (393216 + 67108864)

// LDS (bytes): A 256 rows * 192 B = 49152 ; B 128 rows * 256 B = 32768
// idx (1536 B) overlays the B region during the prologue only.
#define AS2     0
#define BS2     49152
#define SMEM2   81920
#define BN2     128

// weight fp32 -> bf16, permuted to tap-major local k, chunked, pre-swizzled
__global__ __launch_bounds__(256) void convert_w2(
    const float* __restrict__ w, unsigned short* __restrict__ wbf2)
{
    int i = blockIdx.x * 256 + threadIdx.x;          // 0 .. 196607
    if (i >= C_OUT_ * KTOT) return;
    int r  = i / KTOT;
    int g  = i - r * KTOT;
    int kc = g / BK;
    int e  = g - kc * BK;           // 0..95, tap-major: e = tap*32 + lc
    int tap = e >> 5;
    int lc  = e & 31;
    int korig = (kc * 32 + lc) * 3 + tap;
    unsigned short v = f2bf(w[r * KTOT + korig]);
    int addr = (r * 192 + e * 2) ^ ((r & 7) << 4);   // byte, within chunk
    wbf2[(kc * 49152 + addr) >> 1] = v;
}

// data fp32 [b][c][n] -> dataT bf16 [b][n][c]
__global__ __launch_bounds__(256) void transpose_data(
    const float* __restrict__ data, unsigned short* __restrict__ dataT)
{
    __shared__ float T[64][68];
    const int bid = blockIdx.x;
    const int b   = bid >> 6;
    const int ct  = (bid & 63) >> 4;     // 0..3
    const int nt  = bid & 15;            // 0..15
    const int c0  = ct * 64, n0 = nt * 64;
    const int t   = threadIdx.x;
    const int row = t >> 2;              // 0..63
    const int q   = t & 3;

    // load 64 c-rows x 64 n-floats, coalesced
    const float* src = data + ((size_t)(b * C_IN_ + c0 + row)) * NPTS + n0 + q * 16;
    #pragma unroll
    for (int j = 0; j < 4; ++j) {
        float4 v = *(const float4*)(src + j * 4);
        *(float4*)&T[row][q * 16 + j * 4] = v;
    }
    __syncthreads();

    // store: row = n, 16 channels per thread (cquad), bf16
    ushort8 o0, o1;
    #pragma unroll
    for (int j = 0; j < 8; ++j)  o0[j] = f2bf(T[q * 16 + j][row]);
    #pragma unroll
    for (int j = 0; j < 8; ++j)  o1[j] = f2bf(T[q * 16 + 8 + j][row]);
    unsigned short* dst = dataT + ((size_t)(b * NPTS) + n0 + row) * C_IN_ + c0 + q * 16;
    *(ushort8*)(dst)     = o0;
    *(ushort8*)(dst + 8) = o1;
}

// 8 waves as 4(m) x 2(n); per-wave output tile 64x64 (mi=4, ni=4).
// BN=128 columns per block; grid = B_ * 8.
__global__ __launch_bounds__(THREADS, 4) void treeconv_mfma2(
    const unsigned short* __restrict__ wbf2,
    const unsigned short* __restrict__ dataT,
    const int*   __restrict__ indexes,
    const float* __restrict__ bias,
    float*       __restrict__ out)
{
    __shared__ alignas(16) unsigned char smem[SMEM2];
    int* idx_s = (int*)(smem + BS2);     // prologue-only overlay

    const int tid = threadIdx.x;
    const int b   = blockIdx.x >> 3;
    const int nt0 = (blockIdx.x & 7) * BN2;

    if (tid < BN2 * 3) {
        int off = nt0 * 3 + tid;
        idx_s[tid] = (off < L_) ? indexes[b * L_ + off] : 0;
    }
    __syncthreads();

    const int lane = tid & 63;
    const int wid  = tid >> 6;
    const int wm   = wid >> 1;     // m base = wm*64
    const int wn   = wid & 1;      // n base = wn*64
    const int l15  = lane & 15;
    const int lg   = lane >> 4;

    // ---- precompute B gather source offsets (chunk-invariant part) ----
    // LDS image wanted: row n, block bi at byte n*256 + (bi ^ (n&7))*16.
    // global_load_lds writes linearly -> lane covering slot s loads the
    // tuple whose block el = (s&15) ^ (n&7)  (clean inversion: pow2 stride).
    unsigned boff[4];
    #pragma unroll
    for (int j = 0; j < 4; ++j) {
        int slot = wid * 256 + j * 64 + lane;        // 0..2047
        int n    = slot >> 4;                        // 0..127
        int el   = (slot & 15) ^ (n & 7);            // 0..15
        int tap  = (el < 12) ? (el >> 2) : 0;        // pad slots load junk
        int q    = el & 3;
        int ix   = idx_s[n * 3 + tap];
        boff[j]  = (unsigned)(ix * (C_IN_ * 2) + q * 16);   // bytes in row
    }
    __syncthreads();    // idx_s reads done before staging overwrites region

    const char* dTb = (const char*)dataT + (size_t)b * NPTS * C_IN_ * 2;
    const char* wsrc = (const char*)wbf2;

    f32x4 acc[4][4];
    #pragma unroll
    for (int mi = 0; mi < 4; ++mi)
        #pragma unroll
        for (int ni = 0; ni < 4; ++ni)
            acc[mi][ni] = (f32x4){0.f, 0.f, 0.f, 0.f};

    for (int kc = 0; kc < NCHUNK; ++kc) {
        // ---- B stage: 4 issues/wave, gathered source, linear LDS dest ----
        #pragma unroll
        for (int j = 0; j < 4; ++j) {
            gload16(dTb + (size_t)kc * 64 + boff[j],
                    smem + BS2 + wid * 4096 + j * 1024);
        }
        // ---- A stage: 6 issues/wave, fully linear copy ----
        #pragma unroll
        for (int i = 0; i < 6; ++i) {
            int off = wid * 6144 + i * 1024;
            gload16(wsrc + (size_t)kc * 49152 + off + lane * 16,
                    smem + AS2 + off);
        }
        __syncthreads();   // compiler drains vmcnt before barrier

        #pragma unroll
        for (int ks = 0; ks < 3; ++ks) {
            const int kb = ks * 64 + lg * 16;        // block byte offset
            bf16x8 bb[4];
            #pragma unroll
            for (int ni = 0; ni < 4; ++ni) {
                int row = wn * 64 + ni * 16 + l15;
                bb[ni] = *(const bf16x8*)(smem + BS2 + row * 256 + (kb ^ ((row & 7) << 4)));
            }
            #pragma unroll
            for (int mi = 0; mi < 4; ++mi) {
                int row = wm * 64 + mi * 16 + l15;
                bf16x8 av = *(const bf16x8*)(smem + ((row * 192 + kb) ^ ((row & 7) << 4)));
                #pragma unroll
                for (int ni = 0; ni < 4; ++ni)
                    acc[mi][ni] = __builtin_amdgcn_mfma_f32_16x16x32_bf16(
                        av, bb[ni], acc[mi][ni], 0, 0, 0);
            }
        }
        __syncthreads();
    }

    float* outB = out + (size_t)b * (C_OUT_ * T_OUT);
    #pragma unroll
    for (int mi = 0; mi < 4; ++mi) {
        #pragma unroll
        for (int r = 0; r < 4; ++r) {
            int o = wm * 64 + mi * 16 + lg * 4 + r;
            float bv = bias[o];
            #pragma unroll
            for (int ni = 0; ni < 4; ++ni) {
                int n = nt0 + wn * 64 + ni * 16 + l15;
                if (n < NTRIP)
                    outB[o * T_OUT + 1 + n] = acc[mi][ni][r] + bv;
            }
        }
    }
}

// ===================== TIER 1/0 (round-2 fallback) =====================
#define BN      64
#define AS_OFF  0
#define BS_OFF  49152
#define IDX_OFF 61440
#define SMEM_BYTES 62208

template<bool PREW>
__global__ __launch_bounds__(THREADS, 4) void treeconv_mfma(
    const float* __restrict__ data,
    const int*   __restrict__ indexes,
    const float* __restrict__ w32,
    const unsigned short* __restrict__ wbf,
    const float* __restrict__ bias,
    float*       __restrict__ out)
{
    __shared__ alignas(16) unsigned char smem[SMEM_BYTES];
    int* idx_s = (int*)(smem + IDX_OFF);

    const int tid = threadIdx.x;
    const int b   = blockIdx.x >> 4;
    const int nt0 = (blockIdx.x & 15) * BN;

    if (tid < BN * 3) {
        int off = nt0 * 3 + tid;
        idx_s[tid] = (off < L_) ? indexes[b * L_ + off] : 0;
    }
    __syncthreads();

    const int lane = tid & 63;
    const int wid  = tid >> 6;
    const int wm   = wid >> 1;
    const int wn   = wid & 1;
    const int l15  = lane & 15;
    const int lg   = lane >> 4;

    f32x4 acc[4][2];
    #pragma unroll
    for (int mi = 0; mi < 4; ++mi)
        #pragma unroll
        for (int ni = 0; ni < 2; ++ni)
            acc[mi][ni] = (f32x4){0.f, 0.f, 0.f, 0.f};

    const float* dataB = data + (size_t)b * (C_IN_ * NPTS);
    const int ar = tid >> 1;
    const int ah = tid & 1;
    const int gn = tid & 63;
    const int g8 = tid >> 6;

    for (int kc = 0; kc < NCHUNK; ++kc) {
        {
            const int ab = ar * 192 + ah * 96;
            const int sw = (ar & 7) << 4;
            if (PREW) {
                const ushort8* src = (const ushort8*)(wbf + ar * KTOT + kc * BK + ah * 48);
                #pragma unroll
                for (int j = 0; j < 6; ++j) {
                    ushort8 v = src[j];
                    *(ushort8*)(smem + ((ab + j * 16) ^ sw)) = v;
                }
            } else {
                const float* src = w32 + ar * KTOT + kc * BK + ah * 48;
                #pragma unroll
                for (int j = 0; j < 6; ++j) {
                    float4 fa = *(const float4*)(src + j * 8);
                    float4 fb = *(const float4*)(src + j * 8 + 4);
                    ushort8 v;
                    v[0] = f2bf(fa.x); v[1] = f2bf(fa.y); v[2] = f2bf(fa.z); v[3] = f2bf(fa.w);
                    v[4] = f2bf(fb.x); v[5] = f2bf(fb.y); v[6] = f2bf(fb.z); v[7] = f2bf(fb.w);
                    *(ushort8*)(smem + ((ab + j * 16) ^ sw)) = v;
                }
            }
        }
        {
            const int* ip = idx_s + gn * 3;
            int ix0 = ip[0], ix1 = ip[1], ix2 = ip[2];
            const float* dp = dataB + (kc * 32 + g8 * 4) * NPTS;
            unsigned short vals[12];
            #pragma unroll
            for (int ci = 0; ci < 4; ++ci) {
                vals[ci * 3 + 0] = f2bf(dp[ix0]);
                vals[ci * 3 + 1] = f2bf(dp[ix1]);
                vals[ci * 3 + 2] = f2bf(dp[ix2]);
                dp += NPTS;
            }
            const int bb = BS_OFF + gn * 192 + g8 * 24;
            const int sw = (gn & 7) << 4;
            #pragma unroll
            for (int q = 0; q < 3; ++q) {
                ushort4v v;
                v[0] = vals[q * 4 + 0]; v[1] = vals[q * 4 + 1];
                v[2] = vals[q * 4 + 2]; v[3] = vals[q * 4 + 3];
                *(ushort4v*)(smem + ((bb + q * 8) ^ sw)) = v;
            }
        }
        __syncthreads();

        #pragma unroll
        for (int ks = 0; ks < 3; ++ks) {
            bf16x8 a[4], bf[2];
            const int kb = ks * 64 + lg * 16;
            #pragma unroll
            for (int mi = 0; mi < 4; ++mi) {
                int row = wm * 64 + mi * 16 + l15;
                a[mi] = *(const bf16x8*)(smem + ((row * 192 + kb) ^ ((row & 7) << 4)));
            }
            #pragma unroll
            for (int ni = 0; ni < 2; ++ni) {
                int row = wn * 32 + ni * 16 + l15;
                bf[ni] = *(const bf16x8*)(smem + ((BS_OFF + row * 192 + kb) ^ ((row & 7) << 4)));
            }
            #pragma unroll
            for (int mi = 0; mi < 4; ++mi)
                #pragma unroll
                for (int ni = 0; ni < 2; ++ni)
                    acc[mi][ni] = __builtin_amdgcn_mfma_f32_16x16x32_bf16(
                        a[mi], bf[ni], acc[mi][ni], 0, 0, 0);
        }
        __syncthreads();
    }

    float* outB = out + (size_t)b * (C_OUT_ * T_OUT);
    #pragma unroll
    for (int mi = 0; mi < 4; ++mi) {
        #pragma unroll
        for (int r = 0; r < 4; ++r) {
            int o = wm * 64 + mi * 16 + lg * 4 + r;
            float bv = bias[o];
            #pragma unroll
            for (int ni = 0; ni < 2; ++ni) {
                int n = nt0 + wn * 32 + ni * 16 + l15;
                if (n < NTRIP)
                    outB[o * T_OUT + 1 + n] = acc[mi][ni][r] + bv;
            }
        }
    }
}

__global__ __launch_bounds__(256) void convert_w(
    const float* __restrict__ w, unsigned short* __restrict__ wbf)
{
    int i = (blockIdx.x * 256 + threadIdx.x) * 4;
    if (i < C_OUT_ * KTOT) {
        float4 f = *(const float4*)(w + i);
        ushort4v v;
        v[0] = f2bf(f.x); v[1] = f2bf(f.y); v[2] = f2bf(f.z); v[3] = f2bf(f.w);
        *(ushort4v*)(wbf + i) = v;
    }
}

__global__ __launch_bounds__(256) void aux_kernel(
    const int* __restrict__ indexes, float* __restrict__ out)
{
    int i = blockIdx.x * 256 + threadIdx.x;
    if (i < B_ * L_)
        out[FEATS_SIZE + i] = (float)indexes[i];
    if (i < B_ * C_OUT_)
        out[(size_t)i * T_OUT] = 0.0f;
}

extern "C" void kernel_launch(void* const* d_in, const int* in_sizes, int n_in,
                              void* d_out, int out_size, void* d_ws, size_t ws_size,
                              hipStream_t stream)
{
    const float* data    = (const float*)d_in[0];
    const int*   indexes = (const int*)d_in[1];
    const float* weight  = (const float*)d_in[2];
    const float* bias    = (const float*)d_in[3];
    float* out = (float*)d_out;

    hipLaunchKernelGGL(aux_kernel, dim3((B_ * L_ + 255) / 256), dim3(256), 0, stream,
                       indexes, out);

    if (ws_size >= (size_t)WS_NEED_T2) {
        unsigned short* wbf2  = (unsigned short*)((char*)d_ws + WOFF_T);
        unsigned short* dataT = (unsigned short*)((char*)d_ws + DOFF_T);
        hipLaunchKernelGGL(convert_w2, dim3((C_OUT_ * KTOT + 255) / 256), dim3(256),
                           0, stream, weight, wbf2);
        hipLaunchKernelGGL(transpose_data, dim3(B_ * 64), dim3(256), 0, stream,
                           data, dataT);
        hipLaunchKernelGGL(treeconv_mfma2, dim3(B_ * 8), dim3(THREADS), 0, stream,
                           wbf2, dataT, indexes, bias, out);
    } else if (ws_size >= (size_t)(C_OUT_ * KTOT * 2)) {
        unsigned short* wbf = (unsigned short*)d_ws;
        hipLaunchKernelGGL(convert_w, dim3((C_OUT_ * KTOT / 4 + 255) / 256), dim3(256),
                           0, stream, weight, wbf);
        hipLaunchKernelGGL((treeconv_mfma<true>), dim3(B_ * 16), dim3(THREADS), 0, stream,
                           data, indexes, weight, wbf, bias, out);
    } else {
        hipLaunchKernelGGL((treeconv_mfma<false>), dim3(B_ * 16), dim3(THREADS), 0, stream,
                           data, indexes, weight, (const unsigned short*)d_ws, bias, out);
    }
}